// Round 3
// baseline (551.608 us; speedup 1.0000x reference)
//
#include <hip/hip_runtime.h>
#include <hip/hip_bf16.h>

#define DIM 64

// ---------------- Kernel 0: detect edge_index element width ----------------
// Harness contract says integer inputs arrive as int32, but probe to be safe:
// under int64 layout the odd 32-bit words (high halves of indices < 2^17)
// are all zero; under int32 layout they are random node ids.
__global__ void detect_layout_kernel(const int* __restrict__ ei32, int n_check,
                                     int* __restrict__ flag) {
  if (threadIdx.x == 0 && blockIdx.x == 0) {
    int any = 0;
    for (int i = 0; i < n_check; ++i) any |= ei32[2 * i + 1];
    *flag = (any == 0) ? 1 : 0;  // 1 => int64 layout, 0 => int32 layout
  }
}

// ---------------- Kernel 1: h = relu(x @ W^T + b) ----------------
// One thread per row. W (64x64) staged in LDS; x row read as float4.
__global__ __launch_bounds__(256) void linear_relu_kernel(
    const float* __restrict__ x, const float* __restrict__ W,
    const float* __restrict__ b, float* __restrict__ h, int N) {
  __shared__ float Ws[DIM * DIM];
  __shared__ float bs[DIM];
  for (int i = threadIdx.x; i < DIM * DIM; i += 256) Ws[i] = W[i];
  if (threadIdx.x < DIM) bs[threadIdx.x] = b[threadIdx.x];
  __syncthreads();

  int row = blockIdx.x * 256 + threadIdx.x;
  if (row >= N) return;

  const float4* xr = (const float4*)(x + (size_t)row * DIM);
  float acc[DIM];
#pragma unroll
  for (int o = 0; o < DIM; ++o) acc[o] = bs[o];

#pragma unroll
  for (int i4 = 0; i4 < DIM / 4; ++i4) {
    float4 xv = xr[i4];
#pragma unroll
    for (int o = 0; o < DIM; ++o) {
      const float* wrow = &Ws[o * DIM + i4 * 4];
      acc[o] = fmaf(xv.x, wrow[0], acc[o]);
      acc[o] = fmaf(xv.y, wrow[1], acc[o]);
      acc[o] = fmaf(xv.z, wrow[2], acc[o]);
      acc[o] = fmaf(xv.w, wrow[3], acc[o]);
    }
  }

  float4* hr = (float4*)(h + (size_t)row * DIM);
#pragma unroll
  for (int o4 = 0; o4 < DIM / 4; ++o4) {
    float4 v;
    v.x = fmaxf(acc[o4 * 4 + 0], 0.0f);
    v.y = fmaxf(acc[o4 * 4 + 1], 0.0f);
    v.z = fmaxf(acc[o4 * 4 + 2], 0.0f);
    v.w = fmaxf(acc[o4 * 4 + 3], 0.0f);
    hr[o4] = v;
  }
}

// Index loader honoring the detected layout.
__device__ __forceinline__ int load_idx(const int* ei32, int is64, size_t pos) {
  // int64 layout: value at 32-bit word 2*pos (little-endian, high word 0)
  return is64 ? ei32[2 * pos] : ei32[pos];
}

// ---------------- Kernel 2: edge scatter-add ----------------
// One wave (64 lanes) per edge; lane = feature dim. Grid-stride over edges.
// msgs = h[target]; atomically added into out[source]; count per source.
__global__ __launch_bounds__(256) void scatter_add_kernel(
    const int* __restrict__ ei32, const int* __restrict__ flag,
    const float* __restrict__ h, float* __restrict__ out,
    int* __restrict__ counts, int E) {
  int lane = threadIdx.x & 63;
  int wave_in_block = threadIdx.x >> 6;
  int waves_total = gridDim.x * 4;
  int is64 = *flag;

  for (int e = blockIdx.x * 4 + wave_in_block; e < E; e += waves_total) {
    int src = load_idx(ei32, is64, (size_t)e);      // row 0: source
    int tgt = load_idx(ei32, is64, (size_t)E + e);  // row 1: target

    if (lane == 0) atomicAdd(&counts[src], 1);

    float v = h[(size_t)tgt * DIM + lane];
    atomicAdd(&out[(size_t)src * DIM + lane], v);
  }
}

// ---------------- Kernel 3: normalize by clamped counts ----------------
__global__ __launch_bounds__(256) void normalize_kernel(
    float* __restrict__ out, const int* __restrict__ counts, int N) {
  int i4 = blockIdx.x * 256 + threadIdx.x;
  if (i4 >= N * (DIM / 4)) return;
  int n = i4 >> 4;
  float c = (float)max(counts[n], 1);
  float4 v = ((float4*)out)[i4];
  v.x = v.x / c;
  v.y = v.y / c;
  v.z = v.z / c;
  v.w = v.w / c;
  ((float4*)out)[i4] = v;
}

extern "C" void kernel_launch(void* const* d_in, const int* in_sizes, int n_in,
                              void* d_out, int out_size, void* d_ws, size_t ws_size,
                              hipStream_t stream) {
  const float* x = (const float*)d_in[0];
  const int* ei32 = (const int*)d_in[1];
  const float* W = (const float*)d_in[2];
  const float* b = (const float*)d_in[3];

  const int N = in_sizes[0] / DIM;  // 100000
  const int E = in_sizes[1] / 2;    // 1600000

  float* out = (float*)d_out;
  // Workspace layout: [h: N*DIM floats][counts: N ints][flag: 1 int]
  float* h = (float*)d_ws;
  int* counts = (int*)((char*)d_ws + (size_t)N * DIM * 4);
  int* flag = counts + N;

  // Zero accumulator (d_out is poisoned 0xAA) and counts.
  hipMemsetAsync(out, 0, (size_t)N * DIM * 4, stream);
  hipMemsetAsync(counts, 0, (size_t)N * 4, stream);

  // Detect int32 vs int64 edge_index layout (device-side, capture-safe).
  detect_layout_kernel<<<1, 64, 0, stream>>>(ei32, min(E, 64), flag);

  // h = relu(x @ W^T + b)
  linear_relu_kernel<<<(N + 255) / 256, 256, 0, stream>>>(x, W, b, h, N);

  // scatter-add messages + counts (cap grid, grid-stride)
  int sblocks = min((E + 3) / 4, 65536);
  scatter_add_kernel<<<sblocks, 256, 0, stream>>>(ei32, flag, h, out, counts, E);

  // out /= max(counts, 1)
  normalize_kernel<<<(N * (DIM / 4) + 255) / 256, 256, 0, stream>>>(out, counts, N);
}

// Round 5
// 444.260 us; speedup vs baseline: 1.2416x; 1.2416x over previous
//
#include <hip/hip_runtime.h>
#include <hip/hip_bf16.h>

#define DIM 64
#define SCAN_B 256

// ---------------- Kernel 0: detect edge_index element width ----------------
// Contract says int inputs arrive as int32; probe to be safe. Under int64
// little-endian layout the odd 32-bit words (high halves of ids < 2^17) are
// all zero; under int32 layout they are random node ids.
__global__ void detect_layout_kernel(const int* __restrict__ ei32,
                                     int* __restrict__ flag) {
  int v = ei32[2 * threadIdx.x + 1];
  unsigned long long m = __ballot(v != 0);
  if (threadIdx.x == 0) *flag = (m == 0ULL) ? 1 : 0;  // 1 => int64 layout
}

__device__ __forceinline__ int load_idx(const int* ei32, int is64, size_t pos) {
  return is64 ? ei32[2 * pos] : ei32[pos];
}

// ---------------- Kernel 1: h = relu(x @ W^T + b) ----------------
__global__ __launch_bounds__(256) void linear_relu_kernel(
    const float* __restrict__ x, const float* __restrict__ W,
    const float* __restrict__ b, float* __restrict__ h, int N) {
  __shared__ float Ws[DIM * DIM];
  __shared__ float bs[DIM];
  for (int i = threadIdx.x; i < DIM * DIM; i += 256) Ws[i] = W[i];
  if (threadIdx.x < DIM) bs[threadIdx.x] = b[threadIdx.x];
  __syncthreads();

  int row = blockIdx.x * 256 + threadIdx.x;
  if (row >= N) return;

  const float4* xr = (const float4*)(x + (size_t)row * DIM);
  float acc[DIM];
#pragma unroll
  for (int o = 0; o < DIM; ++o) acc[o] = bs[o];

#pragma unroll
  for (int i4 = 0; i4 < DIM / 4; ++i4) {
    float4 xv = xr[i4];
#pragma unroll
    for (int o = 0; o < DIM; ++o) {
      const float* wrow = &Ws[o * DIM + i4 * 4];
      acc[o] = fmaf(xv.x, wrow[0], acc[o]);
      acc[o] = fmaf(xv.y, wrow[1], acc[o]);
      acc[o] = fmaf(xv.z, wrow[2], acc[o]);
      acc[o] = fmaf(xv.w, wrow[3], acc[o]);
    }
  }

  float4* hr = (float4*)(h + (size_t)row * DIM);
#pragma unroll
  for (int o4 = 0; o4 < DIM / 4; ++o4) {
    float4 v;
    v.x = fmaxf(acc[o4 * 4 + 0], 0.0f);
    v.y = fmaxf(acc[o4 * 4 + 1], 0.0f);
    v.z = fmaxf(acc[o4 * 4 + 2], 0.0f);
    v.w = fmaxf(acc[o4 * 4 + 3], 0.0f);
    hr[o4] = v;
  }
}

// ---------------- Kernel 2: histogram of source ids ----------------
__global__ __launch_bounds__(256) void hist_kernel(
    const int* __restrict__ ei32, const int* __restrict__ flag,
    int* __restrict__ counts, int E) {
  int is64 = *flag;
  int i = blockIdx.x * 256 + threadIdx.x;
  int stride = gridDim.x * 256;
  for (int e = i; e < E; e += stride) {
    int src = load_idx(ei32, is64, (size_t)e);
    atomicAdd(&counts[src], 1);
  }
}

// ---------------- Scan (3 kernels): offsets = exclusive_scan(counts) -------
__global__ void scan1_kernel(const int* __restrict__ counts,
                             int* __restrict__ offsets,
                             int* __restrict__ partials, int N) {
  __shared__ int s[SCAN_B];
  int t = threadIdx.x;
  int i = blockIdx.x * SCAN_B + t;
  int v = (i < N) ? counts[i] : 0;
  s[t] = v;
  __syncthreads();
  for (int off = 1; off < SCAN_B; off <<= 1) {
    int add = (t >= off) ? s[t - off] : 0;
    __syncthreads();
    s[t] += add;
    __syncthreads();
  }
  if (i < N) offsets[i] = s[t] - v;  // exclusive within block
  if (t == SCAN_B - 1) partials[blockIdx.x] = s[t];
}

__global__ void scan2_kernel(int* __restrict__ partials, int nb) {
  __shared__ int s[512];
  int t = threadIdx.x;
  int v = (t < nb) ? partials[t] : 0;
  s[t] = v;
  __syncthreads();
  for (int off = 1; off < 512; off <<= 1) {
    int add = (t >= off) ? s[t - off] : 0;
    __syncthreads();
    s[t] += add;
    __syncthreads();
  }
  if (t < nb) partials[t] = s[t] - v;  // exclusive
}

__global__ void scan3_kernel(int* __restrict__ offsets,
                             const int* __restrict__ partials,
                             int* __restrict__ cursor, int N) {
  int i = blockIdx.x * SCAN_B + threadIdx.x;
  if (i < N) {
    int o = offsets[i] + partials[blockIdx.x];
    offsets[i] = o;
    cursor[i] = o;
  }
}

// ---------------- Kernel 3: bucket-fill (counting sort of targets) ---------
__global__ __launch_bounds__(256) void fill_kernel(
    const int* __restrict__ ei32, const int* __restrict__ flag,
    int* __restrict__ cursor, int* __restrict__ bucket, int E) {
  int is64 = *flag;
  int i = blockIdx.x * 256 + threadIdx.x;
  int stride = gridDim.x * 256;
  for (int e = i; e < E; e += stride) {
    int src = load_idx(ei32, is64, (size_t)e);
    int tgt = load_idx(ei32, is64, (size_t)E + e);
    int pos = atomicAdd(&cursor[src], 1);
    bucket[pos] = tgt;
  }
}

// ---------------- Kernel 4: per-node gather + mean ----------------
// One wave per node; lane = feature dim. Lanes cooperatively vector-load up
// to 64 target ids, broadcast via shfl, accumulate h rows in registers.
__global__ __launch_bounds__(256) void gather_kernel(
    const float* __restrict__ h, const int* __restrict__ offsets,
    const int* __restrict__ counts, const int* __restrict__ bucket,
    float* __restrict__ out, int N) {
  int wid = (blockIdx.x * 256 + threadIdx.x) >> 6;
  int lane = threadIdx.x & 63;
  if (wid >= N) return;

  int deg = counts[wid];
  int start = offsets[wid];
  float acc = 0.0f;

  for (int j0 = 0; j0 < deg; j0 += 64) {
    int m = min(deg - j0, 64);
    int t = (lane < m) ? bucket[start + j0 + lane] : 0;
    for (int j = 0; j < m; ++j) {
      int tgt = __shfl(t, j);
      acc += h[(size_t)tgt * DIM + lane];
    }
  }

  float c = (float)max(deg, 1);
  out[(size_t)wid * DIM + lane] = acc / c;
}

extern "C" void kernel_launch(void* const* d_in, const int* in_sizes, int n_in,
                              void* d_out, int out_size, void* d_ws, size_t ws_size,
                              hipStream_t stream) {
  const float* x = (const float*)d_in[0];
  const int* ei32 = (const int*)d_in[1];
  const float* W = (const float*)d_in[2];
  const float* b = (const float*)d_in[3];

  const int N = in_sizes[0] / DIM;  // 100000
  const int E = in_sizes[1] / 2;    // 1600000

  float* out = (float*)d_out;

  // Workspace layout (16B-aligned segments):
  char* p = (char*)d_ws;
  float* h = (float*)p;              p += (size_t)N * DIM * 4;   // 25.6 MB
  int* counts = (int*)p;             p += (size_t)N * 4;
  int* offsets = (int*)p;            p += (size_t)N * 4;
  int* cursor = (int*)p;             p += (size_t)N * 4;
  int* partials = (int*)p;           p += 512 * 4;
  int* flag = (int*)p;               p += 16;
  int* bucket = (int*)p;             /* E ints = 6.4 MB */

  const int nb1 = (N + SCAN_B - 1) / SCAN_B;  // 391

  hipMemsetAsync(counts, 0, (size_t)N * 4, stream);

  detect_layout_kernel<<<1, 64, 0, stream>>>(ei32, flag);

  linear_relu_kernel<<<(N + 255) / 256, 256, 0, stream>>>(x, W, b, h, N);

  hist_kernel<<<2048, 256, 0, stream>>>(ei32, flag, counts, E);

  scan1_kernel<<<nb1, SCAN_B, 0, stream>>>(counts, offsets, partials, N);
  scan2_kernel<<<1, 512, 0, stream>>>(partials, nb1);
  scan3_kernel<<<nb1, SCAN_B, 0, stream>>>(offsets, partials, cursor, N);

  fill_kernel<<<2048, 256, 0, stream>>>(ei32, flag, cursor, bucket, E);

  gather_kernel<<<(N * 64 + 255) / 256, 256, 0, stream>>>(h, offsets, counts,
                                                          bucket, out, N);
}

// Round 6
// 362.059 us; speedup vs baseline: 1.5235x; 1.2270x over previous
//
#include <hip/hip_runtime.h>
#include <hip/hip_bf16.h>

#define DIM 64
#define SCAN_B 256

// ---------------- Kernel 0: detect edge_index element width ----------------
// Contract says int inputs arrive as int32; probe to be safe. Under int64
// little-endian layout the odd 32-bit words (high halves of ids < 2^17) are
// all zero; under int32 layout they are random node ids.
__global__ void detect_layout_kernel(const int* __restrict__ ei32,
                                     int* __restrict__ flag) {
  int v = ei32[2 * threadIdx.x + 1];
  unsigned long long m = __ballot(v != 0);
  if (threadIdx.x == 0) *flag = (m == 0ULL) ? 1 : 0;  // 1 => int64 layout
}

__device__ __forceinline__ int load_idx(const int* ei32, int is64, size_t pos) {
  return is64 ? ei32[2 * pos] : ei32[pos];
}

// ---------------- Kernel 1: histogram + per-edge rank ----------------
// The returning atomic lives HERE, decoupled from the scatter store.
// rank[] is written fully coalesced. 1 edge/thread; TLP hides latency.
__global__ __launch_bounds__(256) void hist_rank_kernel(
    const int* __restrict__ ei32, const int* __restrict__ flag,
    int* __restrict__ counts, int* __restrict__ rank, int E) {
  int e = blockIdx.x * 256 + threadIdx.x;
  if (e >= E) return;
  int src = load_idx(ei32, *flag, (size_t)e);
  rank[e] = atomicAdd(&counts[src], 1);
}

// ---------------- Scan (3 kernels): offsets = exclusive_scan(counts) -------
__global__ void scan1_kernel(const int* __restrict__ counts,
                             int* __restrict__ offsets,
                             int* __restrict__ partials, int N) {
  __shared__ int s[SCAN_B];
  int t = threadIdx.x;
  int i = blockIdx.x * SCAN_B + t;
  int v = (i < N) ? counts[i] : 0;
  s[t] = v;
  __syncthreads();
  for (int off = 1; off < SCAN_B; off <<= 1) {
    int add = (t >= off) ? s[t - off] : 0;
    __syncthreads();
    s[t] += add;
    __syncthreads();
  }
  if (i < N) offsets[i] = s[t] - v;  // exclusive within block
  if (t == SCAN_B - 1) partials[blockIdx.x] = s[t];
}

__global__ void scan2_kernel(int* __restrict__ partials, int nb) {
  __shared__ int s[512];
  int t = threadIdx.x;
  int v = (t < nb) ? partials[t] : 0;
  s[t] = v;
  __syncthreads();
  for (int off = 1; off < 512; off <<= 1) {
    int add = (t >= off) ? s[t - off] : 0;
    __syncthreads();
    s[t] += add;
    __syncthreads();
  }
  if (t < nb) partials[t] = s[t] - v;  // exclusive
}

__global__ void scan3_kernel(int* __restrict__ offsets,
                             const int* __restrict__ partials, int N) {
  int i = blockIdx.x * SCAN_B + threadIdx.x;
  if (i < N) offsets[i] += partials[blockIdx.x];
}

// ---------------- Kernel 2: place (atomic-free scatter) ----------------
// pos is fully determined by offsets[src] + rank[e]; the store is
// fire-and-forget (nontemporal hint — bucket is read once, later).
__global__ __launch_bounds__(256) void place_kernel(
    const int* __restrict__ ei32, const int* __restrict__ flag,
    const int* __restrict__ offsets, const int* __restrict__ rank,
    int* __restrict__ bucket, int E) {
  int e = blockIdx.x * 256 + threadIdx.x;
  if (e >= E) return;
  int is64 = *flag;
  int src = load_idx(ei32, is64, (size_t)e);
  int tgt = load_idx(ei32, is64, (size_t)E + e);
  __builtin_nontemporal_store(tgt, &bucket[offsets[src] + rank[e]]);
}

// ---------------- Kernel 3: h = relu(x @ W^T + b) ----------------
// Runs AFTER place so h's buffer can alias rank[].
__global__ __launch_bounds__(256) void linear_relu_kernel(
    const float* __restrict__ x, const float* __restrict__ W,
    const float* __restrict__ b, float* __restrict__ h, int N) {
  __shared__ float Ws[DIM * DIM];
  __shared__ float bs[DIM];
  for (int i = threadIdx.x; i < DIM * DIM; i += 256) Ws[i] = W[i];
  if (threadIdx.x < DIM) bs[threadIdx.x] = b[threadIdx.x];
  __syncthreads();

  int row = blockIdx.x * 256 + threadIdx.x;
  if (row >= N) return;

  const float4* xr = (const float4*)(x + (size_t)row * DIM);
  float acc[DIM];
#pragma unroll
  for (int o = 0; o < DIM; ++o) acc[o] = bs[o];

#pragma unroll
  for (int i4 = 0; i4 < DIM / 4; ++i4) {
    float4 xv = xr[i4];
#pragma unroll
    for (int o = 0; o < DIM; ++o) {
      const float* wrow = &Ws[o * DIM + i4 * 4];
      acc[o] = fmaf(xv.x, wrow[0], acc[o]);
      acc[o] = fmaf(xv.y, wrow[1], acc[o]);
      acc[o] = fmaf(xv.z, wrow[2], acc[o]);
      acc[o] = fmaf(xv.w, wrow[3], acc[o]);
    }
  }

  float4* hr = (float4*)(h + (size_t)row * DIM);
#pragma unroll
  for (int o4 = 0; o4 < DIM / 4; ++o4) {
    float4 v;
    v.x = fmaxf(acc[o4 * 4 + 0], 0.0f);
    v.y = fmaxf(acc[o4 * 4 + 1], 0.0f);
    v.z = fmaxf(acc[o4 * 4 + 2], 0.0f);
    v.w = fmaxf(acc[o4 * 4 + 3], 0.0f);
    hr[o4] = v;
  }
}

// ---------------- Kernel 4: per-node gather + mean ----------------
// One wave per node; lane = feature dim. Lanes cooperatively vector-load up
// to 64 target ids, broadcast via shfl, accumulate h rows in registers.
__global__ __launch_bounds__(256) void gather_kernel(
    const float* __restrict__ h, const int* __restrict__ offsets,
    const int* __restrict__ counts, const int* __restrict__ bucket,
    float* __restrict__ out, int N) {
  int wid = (blockIdx.x * 256 + threadIdx.x) >> 6;
  int lane = threadIdx.x & 63;
  if (wid >= N) return;

  int deg = counts[wid];
  int start = offsets[wid];
  float acc = 0.0f;

  for (int j0 = 0; j0 < deg; j0 += 64) {
    int m = min(deg - j0, 64);
    int t = (lane < m) ? bucket[start + j0 + lane] : 0;
    for (int j = 0; j < m; ++j) {
      int tgt = __shfl(t, j);
      acc += h[(size_t)tgt * DIM + lane];
    }
  }

  float c = (float)max(deg, 1);
  out[(size_t)wid * DIM + lane] = acc / c;
}

extern "C" void kernel_launch(void* const* d_in, const int* in_sizes, int n_in,
                              void* d_out, int out_size, void* d_ws, size_t ws_size,
                              hipStream_t stream) {
  const float* x = (const float*)d_in[0];
  const int* ei32 = (const int*)d_in[1];
  const float* W = (const float*)d_in[2];
  const float* b = (const float*)d_in[3];

  const int N = in_sizes[0] / DIM;  // 100000
  const int E = in_sizes[1] / 2;    // 1600000

  float* out = (float*)d_out;

  // Workspace layout (total ~32.9 MB, same footprint as the proven round-3):
  //   [bucket E][counts N][offsets N][partials 512][flag][h N*DIM]
  // rank[] aliases h's first E ints (h is computed after place consumes rank).
  char* p = (char*)d_ws;
  int* bucket = (int*)p;   p += (size_t)E * 4;
  int* counts = (int*)p;   p += (size_t)N * 4;
  int* offsets = (int*)p;  p += (size_t)N * 4;
  int* partials = (int*)p; p += 512 * 4;
  int* flag = (int*)p;     p += 16;
  p = (char*)(((uintptr_t)p + 15) & ~(uintptr_t)15);
  float* h = (float*)p;
  int* rank = (int*)p;  // aliases h, dead after place_kernel

  const int nb1 = (N + SCAN_B - 1) / SCAN_B;  // 391
  const int eb = (E + 255) / 256;             // 6250

  hipMemsetAsync(counts, 0, (size_t)N * 4, stream);

  detect_layout_kernel<<<1, 64, 0, stream>>>(ei32, flag);

  hist_rank_kernel<<<eb, 256, 0, stream>>>(ei32, flag, counts, rank, E);

  scan1_kernel<<<nb1, SCAN_B, 0, stream>>>(counts, offsets, partials, N);
  scan2_kernel<<<1, 512, 0, stream>>>(partials, nb1);
  scan3_kernel<<<nb1, SCAN_B, 0, stream>>>(offsets, partials, N);

  place_kernel<<<eb, 256, 0, stream>>>(ei32, flag, offsets, rank, bucket, E);

  linear_relu_kernel<<<(N + 255) / 256, 256, 0, stream>>>(x, W, b, h, N);

  gather_kernel<<<(N * 64 + 255) / 256, 256, 0, stream>>>(h, offsets, counts,
                                                          bucket, out, N);
}

// Round 9
// 329.951 us; speedup vs baseline: 1.6718x; 1.0973x over previous
//
#include <hip/hip_runtime.h>
#include <hip/hip_bf16.h>

#define DIM 64
#define SCAN_B 256

// ---------------- Kernel 0: detect edge_index element width ----------------
__global__ void detect_layout_kernel(const int* __restrict__ ei32,
                                     int* __restrict__ flag) {
  int v = ei32[2 * threadIdx.x + 1];
  unsigned long long m = __ballot(v != 0);
  if (threadIdx.x == 0) *flag = (m == 0ULL) ? 1 : 0;  // 1 => int64 layout
}

__device__ __forceinline__ int load_idx(const int* ei32, int is64, size_t pos) {
  return is64 ? ei32[2 * pos] : ei32[pos];
}

// ---------------- Kernel 1: histogram + per-edge rank ----------------
__global__ __launch_bounds__(256) void hist_rank_kernel(
    const int* __restrict__ ei32, const int* __restrict__ flag,
    int* __restrict__ counts, int* __restrict__ rank, int E) {
  int e = blockIdx.x * 256 + threadIdx.x;
  if (e >= E) return;
  int src = load_idx(ei32, *flag, (size_t)e);
  rank[e] = atomicAdd(&counts[src], 1);
}

// ---------------- Scan (3 kernels): offsets = exclusive_scan(counts) -------
__global__ void scan1_kernel(const int* __restrict__ counts,
                             int* __restrict__ offsets,
                             int* __restrict__ partials, int N) {
  __shared__ int s[SCAN_B];
  int t = threadIdx.x;
  int i = blockIdx.x * SCAN_B + t;
  int v = (i < N) ? counts[i] : 0;
  s[t] = v;
  __syncthreads();
  for (int off = 1; off < SCAN_B; off <<= 1) {
    int add = (t >= off) ? s[t - off] : 0;
    __syncthreads();
    s[t] += add;
    __syncthreads();
  }
  if (i < N) offsets[i] = s[t] - v;  // exclusive within block
  if (t == SCAN_B - 1) partials[blockIdx.x] = s[t];
}

__global__ void scan2_kernel(int* __restrict__ partials, int nb) {
  __shared__ int s[512];
  int t = threadIdx.x;
  int v = (t < nb) ? partials[t] : 0;
  s[t] = v;
  __syncthreads();
  for (int off = 1; off < 512; off <<= 1) {
    int add = (t >= off) ? s[t - off] : 0;
    __syncthreads();
    s[t] += add;
    __syncthreads();
  }
  if (t < nb) partials[t] = s[t] - v;  // exclusive
}

__global__ void scan3_kernel(int* __restrict__ offsets,
                             const int* __restrict__ partials, int N) {
  int i = blockIdx.x * SCAN_B + threadIdx.x;
  if (i < N) offsets[i] += partials[blockIdx.x];
}

// ---------------- Kernel 2: place (atomic-free scatter) ----------------
__global__ __launch_bounds__(256) void place_kernel(
    const int* __restrict__ ei32, const int* __restrict__ flag,
    const int* __restrict__ offsets, const int* __restrict__ rank,
    int* __restrict__ bucket, int E) {
  int e = blockIdx.x * 256 + threadIdx.x;
  if (e >= E) return;
  int is64 = *flag;
  int src = load_idx(ei32, is64, (size_t)e);
  int tgt = load_idx(ei32, is64, (size_t)E + e);
  __builtin_nontemporal_store(tgt, &bucket[offsets[src] + rank[e]]);
}

// ---------------- Kernel 3: h = relu(x @ W^T + b) ----------------
__global__ __launch_bounds__(256) void linear_relu_kernel(
    const float* __restrict__ x, const float* __restrict__ W,
    const float* __restrict__ b, float* __restrict__ h, int N) {
  __shared__ float Ws[DIM * DIM];
  __shared__ float bs[DIM];
  for (int i = threadIdx.x; i < DIM * DIM; i += 256) Ws[i] = W[i];
  if (threadIdx.x < DIM) bs[threadIdx.x] = b[threadIdx.x];
  __syncthreads();

  int row = blockIdx.x * 256 + threadIdx.x;
  if (row >= N) return;

  const float4* xr = (const float4*)(x + (size_t)row * DIM);
  float acc[DIM];
#pragma unroll
  for (int o = 0; o < DIM; ++o) acc[o] = bs[o];

#pragma unroll
  for (int i4 = 0; i4 < DIM / 4; ++i4) {
    float4 xv = xr[i4];
#pragma unroll
    for (int o = 0; o < DIM; ++o) {
      const float* wrow = &Ws[o * DIM + i4 * 4];
      acc[o] = fmaf(xv.x, wrow[0], acc[o]);
      acc[o] = fmaf(xv.y, wrow[1], acc[o]);
      acc[o] = fmaf(xv.z, wrow[2], acc[o]);
      acc[o] = fmaf(xv.w, wrow[3], acc[o]);
    }
  }

  float4* hr = (float4*)(h + (size_t)row * DIM);
#pragma unroll
  for (int o4 = 0; o4 < DIM / 4; ++o4) {
    float4 v;
    v.x = fmaxf(acc[o4 * 4 + 0], 0.0f);
    v.y = fmaxf(acc[o4 * 4 + 1], 0.0f);
    v.z = fmaxf(acc[o4 * 4 + 2], 0.0f);
    v.w = fmaxf(acc[o4 * 4 + 3], 0.0f);
    hr[o4] = v;
  }
}

// ---------------- Kernel 4: per-node gather + mean ----------------
// One wave per node; lane = feature dim. 4 independent accumulators break
// the load->add dependency chain: 4 loads in flight per wave (latency was
// the round-6 limiter: VALUBusy 22%, 2.6 TB/s, FETCH L3-resident).
__global__ __launch_bounds__(256) void gather_kernel(
    const float* __restrict__ h, const int* __restrict__ offsets,
    const int* __restrict__ counts, const int* __restrict__ bucket,
    float* __restrict__ out, int N) {
  int wid = (blockIdx.x * 256 + threadIdx.x) >> 6;
  int lane = threadIdx.x & 63;
  if (wid >= N) return;

  int deg = counts[wid];
  int start = offsets[wid];
  float a0 = 0.0f, a1 = 0.0f, a2 = 0.0f, a3 = 0.0f;

  for (int j0 = 0; j0 < deg; j0 += 64) {
    int m = min(deg - j0, 64);
    int t = (lane < m) ? __builtin_nontemporal_load(&bucket[start + j0 + lane])
                       : 0;
    int j = 0;
    for (; j + 4 <= m; j += 4) {
      int t0 = __shfl(t, j);
      int t1 = __shfl(t, j + 1);
      int t2 = __shfl(t, j + 2);
      int t3 = __shfl(t, j + 3);
      float v0 = h[(size_t)t0 * DIM + lane];
      float v1 = h[(size_t)t1 * DIM + lane];
      float v2 = h[(size_t)t2 * DIM + lane];
      float v3 = h[(size_t)t3 * DIM + lane];
      a0 += v0;
      a1 += v1;
      a2 += v2;
      a3 += v3;
    }
    for (; j < m; ++j) {
      int tj = __shfl(t, j);
      a0 += h[(size_t)tj * DIM + lane];
    }
  }

  float c = (float)max(deg, 1);
  float acc = (a0 + a1) + (a2 + a3);
  __builtin_nontemporal_store(acc / c, &out[(size_t)wid * DIM + lane]);
}

extern "C" void kernel_launch(void* const* d_in, const int* in_sizes, int n_in,
                              void* d_out, int out_size, void* d_ws, size_t ws_size,
                              hipStream_t stream) {
  const float* x = (const float*)d_in[0];
  const int* ei32 = (const int*)d_in[1];
  const float* W = (const float*)d_in[2];
  const float* b = (const float*)d_in[3];

  const int N = in_sizes[0] / DIM;  // 100000
  const int E = in_sizes[1] / 2;    // 1600000

  float* out = (float*)d_out;

  // Workspace layout:
  //   [bucket E][counts N][offsets N][partials 512][flag][h N*DIM]
  // rank[] aliases h (h computed after place consumes rank).
  char* p = (char*)d_ws;
  int* bucket = (int*)p;   p += (size_t)E * 4;
  int* counts = (int*)p;   p += (size_t)N * 4;
  int* offsets = (int*)p;  p += (size_t)N * 4;
  int* partials = (int*)p; p += 512 * 4;
  int* flag = (int*)p;     p += 16;
  p = (char*)(((uintptr_t)p + 15) & ~(uintptr_t)15);
  float* h = (float*)p;
  int* rank = (int*)p;  // aliases h, dead after place_kernel

  const int nb1 = (N + SCAN_B - 1) / SCAN_B;  // 391
  const int eb = (E + 255) / 256;             // 6250

  hipMemsetAsync(counts, 0, (size_t)N * 4, stream);

  detect_layout_kernel<<<1, 64, 0, stream>>>(ei32, flag);

  hist_rank_kernel<<<eb, 256, 0, stream>>>(ei32, flag, counts, rank, E);

  scan1_kernel<<<nb1, SCAN_B, 0, stream>>>(counts, offsets, partials, N);
  scan2_kernel<<<1, 512, 0, stream>>>(partials, nb1);
  scan3_kernel<<<nb1, SCAN_B, 0, stream>>>(offsets, partials, N);

  place_kernel<<<eb, 256, 0, stream>>>(ei32, flag, offsets, rank, bucket, E);

  linear_relu_kernel<<<(N + 255) / 256, 256, 0, stream>>>(x, W, b, h, N);

  gather_kernel<<<(N * 64 + 255) / 256, 256, 0, stream>>>(h, offsets, counts,
                                                          bucket, out, N);
}

// Round 10
// 308.225 us; speedup vs baseline: 1.7896x; 1.0705x over previous
//
#include <hip/hip_runtime.h>
#include <hip/hip_bf16.h>

#define DIM 64
#define SCAN_B 256

// ---------------- Kernel 0: detect edge_index element width ----------------
__global__ void detect_layout_kernel(const int* __restrict__ ei32,
                                     int* __restrict__ flag) {
  int v = ei32[2 * threadIdx.x + 1];
  unsigned long long m = __ballot(v != 0);
  if (threadIdx.x == 0) *flag = (m == 0ULL) ? 1 : 0;  // 1 => int64 layout
}

__device__ __forceinline__ int load_idx(const int* ei32, int is64, size_t pos) {
  return is64 ? ei32[2 * pos] : ei32[pos];
}

// ---------------- Kernel 1 (fused): linear_relu ∥ hist_rank ----------------
// Blocks [0, nbLin) compute h = relu(x @ W^T + b); blocks [nbLin, ...) do the
// histogram + per-edge rank. The two are data-independent; fusing lets them
// overlap instead of serializing on the stream. rank[] lives in d_out (free
// scratch until gather writes the final output).
__global__ __launch_bounds__(256) void lin_hist_kernel(
    const float* __restrict__ x, const float* __restrict__ W,
    const float* __restrict__ b, float* __restrict__ h, int N, int nbLin,
    const int* __restrict__ ei32, const int* __restrict__ flag,
    int* __restrict__ counts, int* __restrict__ rank, int E) {
  __shared__ float Ws[DIM * DIM];
  __shared__ float bs[DIM];

  if (blockIdx.x >= nbLin) {
    // ---- hist_rank path ----
    int e = (blockIdx.x - nbLin) * 256 + threadIdx.x;
    if (e < E) {
      int src = load_idx(ei32, *flag, (size_t)e);
      int r = atomicAdd(&counts[src], 1);
      __builtin_nontemporal_store(r, &rank[e]);
    }
    return;
  }

  // ---- linear_relu path ----
  for (int i = threadIdx.x; i < DIM * DIM; i += 256) Ws[i] = W[i];
  if (threadIdx.x < DIM) bs[threadIdx.x] = b[threadIdx.x];
  __syncthreads();

  int row = blockIdx.x * 256 + threadIdx.x;
  if (row >= N) return;

  const float4* xr = (const float4*)(x + (size_t)row * DIM);
  float acc[DIM];
#pragma unroll
  for (int o = 0; o < DIM; ++o) acc[o] = bs[o];

#pragma unroll
  for (int i4 = 0; i4 < DIM / 4; ++i4) {
    float4 xv = xr[i4];
#pragma unroll
    for (int o = 0; o < DIM; ++o) {
      const float* wrow = &Ws[o * DIM + i4 * 4];
      acc[o] = fmaf(xv.x, wrow[0], acc[o]);
      acc[o] = fmaf(xv.y, wrow[1], acc[o]);
      acc[o] = fmaf(xv.z, wrow[2], acc[o]);
      acc[o] = fmaf(xv.w, wrow[3], acc[o]);
    }
  }

  float4* hr = (float4*)(h + (size_t)row * DIM);
#pragma unroll
  for (int o4 = 0; o4 < DIM / 4; ++o4) {
    float4 v;
    v.x = fmaxf(acc[o4 * 4 + 0], 0.0f);
    v.y = fmaxf(acc[o4 * 4 + 1], 0.0f);
    v.z = fmaxf(acc[o4 * 4 + 2], 0.0f);
    v.w = fmaxf(acc[o4 * 4 + 3], 0.0f);
    hr[o4] = v;
  }
}

// ---------------- Scan (3 kernels): offsets = exclusive_scan(counts) -------
__global__ void scan1_kernel(const int* __restrict__ counts,
                             int* __restrict__ offsets,
                             int* __restrict__ partials, int N) {
  __shared__ int s[SCAN_B];
  int t = threadIdx.x;
  int i = blockIdx.x * SCAN_B + t;
  int v = (i < N) ? counts[i] : 0;
  s[t] = v;
  __syncthreads();
  for (int off = 1; off < SCAN_B; off <<= 1) {
    int add = (t >= off) ? s[t - off] : 0;
    __syncthreads();
    s[t] += add;
    __syncthreads();
  }
  if (i < N) offsets[i] = s[t] - v;  // exclusive within block
  if (t == SCAN_B - 1) partials[blockIdx.x] = s[t];
}

__global__ void scan2_kernel(int* __restrict__ partials, int nb) {
  __shared__ int s[512];
  int t = threadIdx.x;
  int v = (t < nb) ? partials[t] : 0;
  s[t] = v;
  __syncthreads();
  for (int off = 1; off < 512; off <<= 1) {
    int add = (t >= off) ? s[t - off] : 0;
    __syncthreads();
    s[t] += add;
    __syncthreads();
  }
  if (t < nb) partials[t] = s[t] - v;  // exclusive
}

__global__ void scan3_kernel(int* __restrict__ offsets,
                             const int* __restrict__ partials, int N) {
  int i = blockIdx.x * SCAN_B + threadIdx.x;
  if (i < N) offsets[i] += partials[blockIdx.x];
}

// ---------------- Kernel 2: place (atomic-free scatter) ----------------
__global__ __launch_bounds__(256) void place_kernel(
    const int* __restrict__ ei32, const int* __restrict__ flag,
    const int* __restrict__ offsets, const int* __restrict__ rank,
    int* __restrict__ bucket, int E) {
  int e = blockIdx.x * 256 + threadIdx.x;
  if (e >= E) return;
  int is64 = *flag;
  int src = load_idx(ei32, is64, (size_t)e);
  int tgt = load_idx(ei32, is64, (size_t)E + e);
  int r = __builtin_nontemporal_load(&rank[e]);
  __builtin_nontemporal_store(tgt, &bucket[offsets[src] + r]);
}

// ---------------- Kernel 3: per-node gather + mean ----------------
// One wave per node; lane = feature dim. 8 independent accumulators keep 8
// loads in flight per wave (round-9: 4-way took 111.7 -> 77.9 us; still
// latency-bound at VALUBusy 26%, 46% HBM peak).
__global__ __launch_bounds__(256) void gather_kernel(
    const float* __restrict__ h, const int* __restrict__ offsets,
    const int* __restrict__ counts, const int* __restrict__ bucket,
    float* __restrict__ out, int N) {
  int wid = (blockIdx.x * 256 + threadIdx.x) >> 6;
  int lane = threadIdx.x & 63;
  if (wid >= N) return;

  int deg = counts[wid];
  int start = offsets[wid];
  float a0 = 0.f, a1 = 0.f, a2 = 0.f, a3 = 0.f;
  float a4 = 0.f, a5 = 0.f, a6 = 0.f, a7 = 0.f;

  for (int j0 = 0; j0 < deg; j0 += 64) {
    int m = min(deg - j0, 64);
    int t = (lane < m) ? __builtin_nontemporal_load(&bucket[start + j0 + lane])
                       : 0;
    int j = 0;
    for (; j + 8 <= m; j += 8) {
      int t0 = __shfl(t, j);
      int t1 = __shfl(t, j + 1);
      int t2 = __shfl(t, j + 2);
      int t3 = __shfl(t, j + 3);
      int t4 = __shfl(t, j + 4);
      int t5 = __shfl(t, j + 5);
      int t6 = __shfl(t, j + 6);
      int t7 = __shfl(t, j + 7);
      float v0 = h[(size_t)t0 * DIM + lane];
      float v1 = h[(size_t)t1 * DIM + lane];
      float v2 = h[(size_t)t2 * DIM + lane];
      float v3 = h[(size_t)t3 * DIM + lane];
      float v4 = h[(size_t)t4 * DIM + lane];
      float v5 = h[(size_t)t5 * DIM + lane];
      float v6 = h[(size_t)t6 * DIM + lane];
      float v7 = h[(size_t)t7 * DIM + lane];
      a0 += v0; a1 += v1; a2 += v2; a3 += v3;
      a4 += v4; a5 += v5; a6 += v6; a7 += v7;
    }
    for (; j < m; ++j) {
      int tj = __shfl(t, j);
      a0 += h[(size_t)tj * DIM + lane];
    }
  }

  float c = (float)max(deg, 1);
  float acc = ((a0 + a1) + (a2 + a3)) + ((a4 + a5) + (a6 + a7));
  __builtin_nontemporal_store(acc / c, &out[(size_t)wid * DIM + lane]);
}

extern "C" void kernel_launch(void* const* d_in, const int* in_sizes, int n_in,
                              void* d_out, int out_size, void* d_ws, size_t ws_size,
                              hipStream_t stream) {
  const float* x = (const float*)d_in[0];
  const int* ei32 = (const int*)d_in[1];
  const float* W = (const float*)d_in[2];
  const float* b = (const float*)d_in[3];

  const int N = in_sizes[0] / DIM;  // 100000
  const int E = in_sizes[1] / 2;    // 1600000

  float* out = (float*)d_out;

  // rank[] borrows d_out: it is produced by lin_hist, consumed by place, and
  // d_out is only written (by gather) strictly after place completes.
  int* rank = (int*)d_out;

  // Workspace: [bucket E][counts N][offsets N][partials 512][flag][h N*DIM]
  char* p = (char*)d_ws;
  int* bucket = (int*)p;   p += (size_t)E * 4;
  int* counts = (int*)p;   p += (size_t)N * 4;
  int* offsets = (int*)p;  p += (size_t)N * 4;
  int* partials = (int*)p; p += 512 * 4;
  int* flag = (int*)p;     p += 16;
  p = (char*)(((uintptr_t)p + 15) & ~(uintptr_t)15);
  float* h = (float*)p;

  const int nb1 = (N + SCAN_B - 1) / SCAN_B;  // 391
  const int eb = (E + 255) / 256;             // 6250
  const int nbLin = (N + 255) / 256;          // 391

  hipMemsetAsync(counts, 0, (size_t)N * 4, stream);

  detect_layout_kernel<<<1, 64, 0, stream>>>(ei32, flag);

  lin_hist_kernel<<<nbLin + eb, 256, 0, stream>>>(x, W, b, h, N, nbLin, ei32,
                                                  flag, counts, rank, E);

  scan1_kernel<<<nb1, SCAN_B, 0, stream>>>(counts, offsets, partials, N);
  scan2_kernel<<<1, 512, 0, stream>>>(partials, nb1);
  scan3_kernel<<<nb1, SCAN_B, 0, stream>>>(offsets, partials, N);

  place_kernel<<<eb, 256, 0, stream>>>(ei32, flag, offsets, rank, bucket, E);

  gather_kernel<<<(N * 64 + 255) / 256, 256, 0, stream>>>(h, offsets, counts,
                                                          bucket, out, N);
}